// Round 2
// baseline (15844.923 us; speedup 1.0000x reference)
//
#include <hip/hip_runtime.h>

// AGGCN: split-precision bf16 MFMA (hi+lo, 3-pass) version.
// N=512, T=12, B=64, DIN=2, H=128, D=16, K=3, 2 layers.
// cin padded: layer0 130->160, layer1 256->256.
// R2: node_mfma grid = (ob FAST, nb). With id%8->XCD round-robin each XCD sees
//     ONE ob strip -> Wr strip (<=3.15MB) stays L2-resident per XCD instead of
//     thrashing to LLC. xgN A-frag loads nontemporal (stream, don't evict Wr).
//     Gate OSTRIP=64 (R0 math, bit-identical); update OSTRIP=32 -> 512 blocks
//     (2 blk/CU, was 1). R1's node-major ostrip-32 gate (HBM 3x refetch) reverted.

constexpr int N_ = 512, T_ = 12, B_ = 64, DIN_ = 2, H_ = 128, D_ = 16, K_ = 3;

typedef __attribute__((ext_vector_type(8))) short short8;
typedef __attribute__((ext_vector_type(4))) short short4v;
typedef __attribute__((ext_vector_type(4))) float floatx4;

__device__ __forceinline__ unsigned short f2bf(float f) {
    unsigned int u = __builtin_bit_cast(unsigned int, f);
    u += 0x7fffu + ((u >> 16) & 1u);
    return (unsigned short)(u >> 16);
}
__device__ __forceinline__ float bf2f(unsigned short h) {
    unsigned int u = ((unsigned int)h) << 16;
    return __builtin_bit_cast(float, u);
}
// split v ~= hi + lo (each bf16); lo captures the hi-rounding residual.
__device__ __forceinline__ void splitbf(float v, unsigned short& hh, unsigned short& ll) {
    hh = f2bf(v);
    ll = f2bf(v - bf2f(hh));
}

// ---------------------------------------------------------------------------
// LayerNorm over D=16 of (node_emb[n] + time_emb[t]) -> ne fp32
__global__ void ln_kernel(const float* __restrict__ nemb, const float* __restrict__ temb,
                          const float* __restrict__ g, const float* __restrict__ b,
                          float* __restrict__ ne) {
    int idx = blockIdx.x * 256 + threadIdx.x;
    if (idx >= T_ * N_) return;
    int t = idx / N_, n = idx % N_;
    float x[D_];
    float m = 0.f;
#pragma unroll
    for (int d = 0; d < D_; d++) { x[d] = nemb[n * D_ + d] + temb[t * D_ + d]; m += x[d]; }
    m *= (1.f / D_);
    float v = 0.f;
#pragma unroll
    for (int d = 0; d < D_; d++) { float c = x[d] - m; v += c * c; }
    v *= (1.f / D_);
    float rs = rsqrtf(v + 1e-12f);
#pragma unroll
    for (int d = 0; d < D_; d++) ne[(long)idx * D_ + d] = (x[d] - m) * rs * g[d] + b[d];
}

// ---------------------------------------------------------------------------
// S[t] = row-softmax(ne[t] @ ne[t]^T) -> bf16 hi/lo planes, row-major [dst][src]
__global__ void support_softmax(const float* __restrict__ ne,
                                unsigned short* __restrict__ Sh, unsigned short* __restrict__ Sl) {
    int rid = blockIdx.x;            // t*N + n
    int t = rid / N_, n = rid % N_;
    const float* net = ne + (long)t * N_ * D_;
    int lane = threadIdx.x;          // 64
    float r[D_];
#pragma unroll
    for (int d = 0; d < D_; d++) r[d] = net[(long)n * D_ + d];
    float v[8];
    float mx = -1e30f;
#pragma unroll
    for (int jj = 0; jj < 8; jj++) {
        const float* nj = net + (long)(jj * 64 + lane) * D_;
        float acc = 0.f;
#pragma unroll
        for (int d = 0; d < D_; d++) acc = fmaf(r[d], nj[d], acc);
        v[jj] = acc;
        mx = fmaxf(mx, acc);
    }
#pragma unroll
    for (int off = 32; off >= 1; off >>= 1) mx = fmaxf(mx, __shfl_xor(mx, off, 64));
    float s = 0.f;
#pragma unroll
    for (int jj = 0; jj < 8; jj++) { v[jj] = __expf(v[jj] - mx); s += v[jj]; }
#pragma unroll
    for (int off = 32; off >= 1; off >>= 1) s += __shfl_xor(s, off, 64);
    float inv = 1.f / s;
#pragma unroll
    for (int jj = 0; jj < 8; jj++) {
        unsigned short hh, ll;
        splitbf(v[jj] * inv, hh, ll);
        Sh[(long)rid * N_ + jj * 64 + lane] = hh;
        Sl[(long)rid * N_ + jj * 64 + lane] = ll;
    }
}

// ---------------------------------------------------------------------------
// W (D,K,cin,out) fp32 -> Wr (K,cinp,out,D) fp32, zero for i>=cin.
__global__ void reorder_W(const float* __restrict__ W, float* __restrict__ Wr,
                          int cin, int cinp, int outdim) {
    int total = K_ * cinp * outdim * D_;
    int idx = blockIdx.x * 256 + threadIdx.x;
    if (idx >= total) return;
    int d = idx & (D_ - 1);
    int rest = idx >> 4;            // (k*cinp + i)*outdim + o
    int o = rest % outdim;
    int ki = rest / outdim;
    int i = ki % cinp, kk = ki / cinp;
    float val = 0.f;
    if (i < cin) val = W[(((long)d * K_ + kk) * cin + i) * outdim + o];
    Wr[idx] = val;
}

// ---------------------------------------------------------------------------
// x0 = concat(xt, (z*)h), split bf16, dual layout:
//  xgN[n][b*cinp+c] (node-major) hi/lo;  xgA[(b*cinp+c)][n] (F-major) hi/lo.
__global__ void build_xcat(unsigned short* __restrict__ xgAh, unsigned short* __restrict__ xgAl,
                           unsigned short* __restrict__ xgNh, unsigned short* __restrict__ xgNl,
                           const void* __restrict__ xt, int xt_i16, long sb, long sn,
                           int cx, int cin, int cinp,
                           const float* __restrict__ h, const float* __restrict__ zr) {
    int n = blockIdx.y;
    int idx = blockIdx.x * 256 + threadIdx.x;   // b*cinp + c (grid exact)
    int b = idx / cinp, c = idx - b * cinp;
    float v = 0.f;
    if (c < cx) {
        v = xt_i16 ? (float)((const short*)xt)[(long)b * sb + (long)n * sn + c] * (1.f / 32767.f)
                   : ((const float*)xt)[(long)b * sb + (long)n * sn + c];
    } else if (c < cin) {
        int q = c - cx;
        v = h[((long)n * B_ + b) * H_ + q];
        if (zr) v *= zr[((long)n * B_ + b) * (2 * H_) + q];
    }
    unsigned short hh, ll;
    splitbf(v, hh, ll);
    xgNh[(long)n * B_ * cinp + idx] = hh;
    xgNl[(long)n * B_ * cinp + idx] = ll;
    xgAh[(long)idx * N_ + n] = hh;
    xgAl[(long)idx * N_ + n] = ll;
}

// ---------------------------------------------------------------------------
// Graph prop, split bf16 3-pass MFMA: out[f,dst] = sum_src X[f,src]*S[dst,src]
// 128x128 tile, BK=32, 4 waves of 64x64 each.
// outN hi/lo: [dst][f]. outA hi/lo: [f][dst] (P1 only).
// subN hi/lo: Chebyshev  val = 2*acc - x0  (P2 only).
__global__ __launch_bounds__(256) void prop_mfma(
    const unsigned short* __restrict__ XAh, const unsigned short* __restrict__ XAl,
    const unsigned short* __restrict__ Sh,  const unsigned short* __restrict__ Sl,
    unsigned short* __restrict__ outAh, unsigned short* __restrict__ outAl,
    unsigned short* __restrict__ outNh, unsigned short* __restrict__ outNl,
    const unsigned short* __restrict__ subNh, const unsigned short* __restrict__ subNl,
    int Fp) {
    __shared__ short Ash[128 * 40];
    __shared__ short Asl[128 * 40];
    __shared__ short Ssh[128 * 40];
    __shared__ short Ssl[128 * 40];
    int tid = threadIdx.x;
    int bm = blockIdx.x * 128, bn = blockIdx.y * 128;
    int w = tid >> 6, lane15 = tid & 15, quad = (tid >> 4) & 3;
    int mw = (w & 1) * 64, nw = (w >> 1) * 64;
    floatx4 acc[4][4];
#pragma unroll
    for (int mt = 0; mt < 4; mt++)
#pragma unroll
        for (int nt = 0; nt < 4; nt++) acc[mt][nt] = (floatx4){0.f, 0.f, 0.f, 0.f};

    for (int s0 = 0; s0 < N_; s0 += 32) {
#pragma unroll
        for (int p = 0; p < 2; p++) {
            int c = tid + p * 256;
            int row = c >> 2, col = (c & 3) * 8;
            *(short8*)&Ash[row * 40 + col] = *(const short8*)(XAh + (long)(bm + row) * N_ + s0 + col);
            *(short8*)&Asl[row * 40 + col] = *(const short8*)(XAl + (long)(bm + row) * N_ + s0 + col);
            *(short8*)&Ssh[row * 40 + col] = *(const short8*)(Sh + (long)(bn + row) * N_ + s0 + col);
            *(short8*)&Ssl[row * 40 + col] = *(const short8*)(Sl + (long)(bn + row) * N_ + s0 + col);
        }
        __syncthreads();
        short8 ah[4], al[4];
#pragma unroll
        for (int mt = 0; mt < 4; mt++) {
            ah[mt] = *(const short8*)&Ash[(mw + mt * 16 + lane15) * 40 + quad * 8];
            al[mt] = *(const short8*)&Asl[(mw + mt * 16 + lane15) * 40 + quad * 8];
        }
#pragma unroll
        for (int nt = 0; nt < 4; nt++) {
            short8 bh = *(const short8*)&Ssh[(nw + nt * 16 + lane15) * 40 + quad * 8];
            short8 bl = *(const short8*)&Ssl[(nw + nt * 16 + lane15) * 40 + quad * 8];
#pragma unroll
            for (int mt = 0; mt < 4; mt++) {
                acc[mt][nt] = __builtin_amdgcn_mfma_f32_16x16x32_bf16(ah[mt], bh, acc[mt][nt], 0, 0, 0);
                acc[mt][nt] = __builtin_amdgcn_mfma_f32_16x16x32_bf16(al[mt], bh, acc[mt][nt], 0, 0, 0);
                acc[mt][nt] = __builtin_amdgcn_mfma_f32_16x16x32_bf16(ah[mt], bl, acc[mt][nt], 0, 0, 0);
            }
        }
        __syncthreads();
    }

#pragma unroll
    for (int mt = 0; mt < 4; mt++) {
        int f0 = bm + mw + mt * 16 + quad * 4;
#pragma unroll
        for (int nt = 0; nt < 4; nt++) {
            int dst = bn + nw + nt * 16 + lane15;
            float v[4] = {acc[mt][nt][0], acc[mt][nt][1], acc[mt][nt][2], acc[mt][nt][3]};
            if (subNh) {
                ushort4 sh4 = *(const ushort4*)(subNh + (long)dst * Fp + f0);
                ushort4 sl4 = *(const ushort4*)(subNl + (long)dst * Fp + f0);
                v[0] = 2.f * v[0] - (bf2f(sh4.x) + bf2f(sl4.x));
                v[1] = 2.f * v[1] - (bf2f(sh4.y) + bf2f(sl4.y));
                v[2] = 2.f * v[2] - (bf2f(sh4.z) + bf2f(sl4.z));
                v[3] = 2.f * v[3] - (bf2f(sh4.w) + bf2f(sl4.w));
            }
            ushort4 oh, ol;
            splitbf(v[0], oh.x, ol.x); splitbf(v[1], oh.y, ol.y);
            splitbf(v[2], oh.z, ol.z); splitbf(v[3], oh.w, ol.w);
            *(ushort4*)(outNh + (long)dst * Fp + f0) = oh;
            *(ushort4*)(outNl + (long)dst * Fp + f0) = ol;
            if (outAh) {
                unsigned short* pah = outAh + (long)f0 * N_ + dst;
                unsigned short* pal = outAl + (long)f0 * N_ + dst;
                pah[0] = oh.x; pah[N_] = oh.y; pah[2 * N_] = oh.z; pah[3 * N_] = oh.w;
                pal[0] = ol.x; pal[N_] = ol.y; pal[2 * N_] = ol.z; pal[3 * N_] = ol.w;
            }
        }
    }
}

// ---------------------------------------------------------------------------
// Fused node GEMM, split precision. Block = 4 nodes (1/wave) x OSTRIP o-cols.
// Pool Wp[i][o] = sum_d ne[n,d]*Wr[k,i,o,d] in fp32 (once per element),
// split into LDS hi/lo; 3-pass 16x16x32 bf16 MFMA vs xgN hi/lo.
// Grid = (ob FAST, nb): with id%8 XCD round-robin every XCD hosts a single ob
// strip, so its Wr slice (<=3.15MB) is L2-resident; xgN re-reads across the
// 4 ob-XCDs are absorbed by the 256MB LLC (xgN unique ~100MB). xgN A-frag
// loads are nontemporal so the stream doesn't evict Wr from L2.
// mode 1: sigmoid -> zrOut(dstF). mode 2: tanh, h'=r*h+(1-r)*hc -> h + dstF|dstI.
template <int OSTRIP>
__global__ __launch_bounds__(256) void node_mfma(
    const unsigned short* __restrict__ xgNh, const unsigned short* __restrict__ xgNl,
    const float* __restrict__ ne_t,
    const float* __restrict__ Wr, const float* __restrict__ bpool,
    int cinp, int outdim, int mode,
    const float* __restrict__ zrIn, float* __restrict__ h,
    float* __restrict__ dstF, short* __restrict__ dstI,
    long dn, long db) {
    constexpr int NT = OSTRIP / 16;     // n-tiles per wave (4 or 2)
    constexpr int IG = 256 / OSTRIP;    // i-groups covering the 32-slab (4 or 8)
    constexpr int IL = 32 / IG;         // i's per thread (8 or 4)
    __shared__ short Wph[4 * OSTRIP * 40];
    __shared__ short Wpl[4 * OSTRIP * 40];
    int tid = threadIdx.x;
    int ob = blockIdx.x * OSTRIP;       // FAST grid dim -> one ob per XCD
    int n0 = blockIdx.y * 4;
    int w = tid >> 6, lane15 = tid & 15, quad = (tid >> 4) & 3;
    int oo = tid & (OSTRIP - 1);        // o within strip
    int iq = tid / OSTRIP;              // i-group
    int Fp = B_ * cinp;
    int myn = n0 + w;

    float ner[4][16];
#pragma unroll
    for (int g = 0; g < 4; g++)
#pragma unroll
        for (int d = 0; d < D_; d++) ner[g][d] = ne_t[(long)(n0 + g) * D_ + d];

    float bias[NT];
#pragma unroll
    for (int nt = 0; nt < NT; nt++) {
        int o = ob + nt * 16 + lane15;
        float bv = 0.f;
#pragma unroll
        for (int d = 0; d < D_; d++) bv = fmaf(ner[w][d], bpool[(long)d * outdim + o], bv);
        bias[nt] = bv;
    }
    floatx4 acc[4][NT];
#pragma unroll
    for (int mt = 0; mt < 4; mt++)
#pragma unroll
        for (int nt = 0; nt < NT; nt++) acc[mt][nt] = (floatx4){bias[nt], bias[nt], bias[nt], bias[nt]};

    for (int kk = 0; kk < K_; kk++) {
        const unsigned short* xbh = xgNh + ((long)kk * N_ + myn) * Fp;
        const unsigned short* xbl = xgNl + ((long)kk * N_ + myn) * Fp;
        for (int i0 = 0; i0 < cinp; i0 += 32) {
            // ---- fp32 pooling: thread covers o=ob+oo, i = i0 + iq*IL + il, all 4 nodes ----
            float pool[4][IL];
#pragma unroll
            for (int g = 0; g < 4; g++)
#pragma unroll
                for (int il = 0; il < IL; il++) pool[g][il] = 0.f;
#pragma unroll
            for (int il = 0; il < IL; il++) {
                const float* wp = Wr + ((long)(kk * cinp + i0 + iq * IL + il) * outdim + ob + oo) * D_;
                float4 w0 = *(const float4*)(wp + 0);
                float4 w1 = *(const float4*)(wp + 4);
                float4 w2 = *(const float4*)(wp + 8);
                float4 w3 = *(const float4*)(wp + 12);
                float wv[16] = {w0.x, w0.y, w0.z, w0.w, w1.x, w1.y, w1.z, w1.w,
                                w2.x, w2.y, w2.z, w2.w, w3.x, w3.y, w3.z, w3.w};
#pragma unroll
                for (int d = 0; d < D_; d++)
#pragma unroll
                    for (int g = 0; g < 4; g++) pool[g][il] = fmaf(ner[g][d], wv[d], pool[g][il]);
            }
            __syncthreads();   // previous slab's frag reads complete
#pragma unroll
            for (int g = 0; g < 4; g++) {
                if constexpr (IL == 8) {
                    short8 vh, vl;
#pragma unroll
                    for (int il = 0; il < 8; il++) {
                        unsigned short hh, ll;
                        splitbf(pool[g][il], hh, ll);
                        vh[il] = (short)hh; vl[il] = (short)ll;
                    }
                    *(short8*)&Wph[(g * OSTRIP + oo) * 40 + iq * 8] = vh;
                    *(short8*)&Wpl[(g * OSTRIP + oo) * 40 + iq * 8] = vl;
                } else {
                    short4v vh, vl;
#pragma unroll
                    for (int il = 0; il < 4; il++) {
                        unsigned short hh, ll;
                        splitbf(pool[g][il], hh, ll);
                        vh[il] = (short)hh; vl[il] = (short)ll;
                    }
                    *(short4v*)&Wph[(g * OSTRIP + oo) * 40 + iq * 4] = vh;
                    *(short4v*)&Wpl[(g * OSTRIP + oo) * 40 + iq * 4] = vl;
                }
            }
            __syncthreads();
            // ---- 3-pass MFMA ----
            short8 ah[4], al[4];
#pragma unroll
            for (int mt = 0; mt < 4; mt++) {
                ah[mt] = __builtin_nontemporal_load(
                    (const short8*)(xbh + (long)(mt * 16 + lane15) * cinp + i0 + quad * 8));
                al[mt] = __builtin_nontemporal_load(
                    (const short8*)(xbl + (long)(mt * 16 + lane15) * cinp + i0 + quad * 8));
            }
#pragma unroll
            for (int nt = 0; nt < NT; nt++) {
                short8 bh = *(const short8*)&Wph[(w * OSTRIP + nt * 16 + lane15) * 40 + quad * 8];
                short8 bl = *(const short8*)&Wpl[(w * OSTRIP + nt * 16 + lane15) * 40 + quad * 8];
#pragma unroll
                for (int mt = 0; mt < 4; mt++) {
                    acc[mt][nt] = __builtin_amdgcn_mfma_f32_16x16x32_bf16(ah[mt], bh, acc[mt][nt], 0, 0, 0);
                    acc[mt][nt] = __builtin_amdgcn_mfma_f32_16x16x32_bf16(al[mt], bh, acc[mt][nt], 0, 0, 0);
                    acc[mt][nt] = __builtin_amdgcn_mfma_f32_16x16x32_bf16(ah[mt], bl, acc[mt][nt], 0, 0, 0);
                }
            }
        }
    }

#pragma unroll
    for (int mt = 0; mt < 4; mt++) {
        int b0 = mt * 16 + quad * 4;
#pragma unroll
        for (int nt = 0; nt < NT; nt++) {
            int o = ob + nt * 16 + lane15;
#pragma unroll
            for (int r = 0; r < 4; r++) {
                float v = acc[mt][nt][r];
                int bb = b0 + r;
                if (mode == 1) {
                    float s = 1.f / (1.f + __expf(-v));
                    dstF[(long)myn * dn + (long)bb * db + o] = s;
                } else {
                    float hc = tanhf(v);
                    long bi = (long)myn * B_ + bb;
                    float rr = zrIn[bi * (2 * H_) + H_ + o];
                    float hn = rr * h[bi * H_ + o] + (1.f - rr) * hc;
                    h[bi * H_ + o] = hn;
                    if (dstF) dstF[(long)myn * dn + (long)bb * db + o] = hn;
                    else {
                        int q = __float2int_rn(hn * 32767.f);
                        q = q > 32767 ? 32767 : (q < -32767 ? -32767 : q);
                        dstI[(long)myn * dn + (long)bb * db + o] = (short)q;
                    }
                }
            }
        }
    }
}

// ---------------------------------------------------------------------------
extern "C" void kernel_launch(void* const* d_in, const int* in_sizes, int n_in,
                              void* d_out, int out_size, void* d_ws, size_t ws_size,
                              hipStream_t stream) {
    const float* source   = (const float*)d_in[0];
    const float* node_emb = (const float*)d_in[1];
    const float* time_emb = (const float*)d_in[2];
    float* out = (float*)d_out;

    char* p = (char*)d_ws;
    auto carve = [&](size_t bytes) { char* r = p; p += (bytes + 255) & ~255ull; return r; };
    float*          ne_g  = (float*)carve((size_t)T_ * N_ * D_ * 4);
    float*          ne_u  = (float*)carve((size_t)T_ * N_ * D_ * 4);
    unsigned short* S_gh  = (unsigned short*)carve((size_t)T_ * N_ * N_ * 2);
    unsigned short* S_gl  = (unsigned short*)carve((size_t)T_ * N_ * N_ * 2);
    unsigned short* S_uh  = (unsigned short*)carve((size_t)T_ * N_ * N_ * 2);
    unsigned short* S_ul  = (unsigned short*)carve((size_t)T_ * N_ * N_ * 2);
    float*          Wr_g  = (float*)carve((size_t)K_ * 256 * 256 * D_ * 4);
    float*          Wr_u  = (float*)carve((size_t)K_ * 256 * 128 * D_ * 4);
    unsigned short* xgA0h = (unsigned short*)carve((size_t)64 * 256 * N_ * 2);
    unsigned short* xgA0l = (unsigned short*)carve((size_t)64 * 256 * N_ * 2);
    unsigned short* xgA1h = (unsigned short*)carve((size_t)64 * 256 * N_ * 2);
    unsigned short* xgA1l = (unsigned short*)carve((size_t)64 * 256 * N_ * 2);
    unsigned short* xgNh  = (unsigned short*)carve((size_t)K_ * N_ * 64 * 256 * 2);
    unsigned short* xgNl  = (unsigned short*)carve((size_t)K_ * N_ * 64 * 256 * 2);
    float*          zr    = (float*)carve((size_t)N_ * B_ * 2 * H_ * 4);
    float*          h     = (float*)carve((size_t)N_ * B_ * H_ * 4);
    short*          cur0  = (short*)carve((size_t)T_ * N_ * B_ * H_ * 2);
    if ((size_t)(p - (char*)d_ws) > ws_size) return;  // ws guard (~364 MB)

    for (int layer = 0; layer < 2; ++layer) {
        const float* gW   = (const float*)d_in[3 + layer * 8 + 0];
        const float* gb   = (const float*)d_in[3 + layer * 8 + 1];
        const float* glng = (const float*)d_in[3 + layer * 8 + 2];
        const float* glnb = (const float*)d_in[3 + layer * 8 + 3];
        const float* uW   = (const float*)d_in[3 + layer * 8 + 4];
        const float* ub   = (const float*)d_in[3 + layer * 8 + 5];
        const float* ulng = (const float*)d_in[3 + layer * 8 + 6];
        const float* ulnb = (const float*)d_in[3 + layer * 8 + 7];
        const int cin  = (layer == 0) ? (DIN_ + H_) : (2 * H_);
        const int cinp = (layer == 0) ? 160 : 256;
        const int cx   = (layer == 0) ? DIN_ : H_;
        const int Fp   = B_ * cinp;
        const long sliceN = (long)N_ * Fp;

        ln_kernel<<<dim3(24), dim3(256), 0, stream>>>(node_emb, time_emb, glng, glnb, ne_g);
        ln_kernel<<<dim3(24), dim3(256), 0, stream>>>(node_emb, time_emb, ulng, ulnb, ne_u);
        support_softmax<<<dim3(T_ * N_), dim3(64), 0, stream>>>(ne_g, S_gh, S_gl);
        support_softmax<<<dim3(T_ * N_), dim3(64), 0, stream>>>(ne_u, S_uh, S_ul);
        reorder_W<<<dim3(K_ * cinp * (2 * H_) * D_ / 256), dim3(256), 0, stream>>>(gW, Wr_g, cin, cinp, 2 * H_);
        reorder_W<<<dim3(K_ * cinp * H_ * D_ / 256), dim3(256), 0, stream>>>(uW, Wr_u, cin, cinp, H_);
        hipMemsetAsync(h, 0, (size_t)N_ * B_ * H_ * sizeof(float), stream);

        for (int t = 0; t < T_; ++t) {
            const void* xt; long sb, sn; int xi16;
            if (layer == 0) { xt = source + (long)t * N_ * DIN_; sb = (long)T_ * N_ * DIN_; sn = DIN_; xi16 = 0; }
            else            { xt = cur0 + (long)t * N_ * B_ * H_; sb = H_; sn = (long)B_ * H_; xi16 = 1; }
            const unsigned short* Sgh = S_gh + (long)t * N_ * N_;
            const unsigned short* Sgl = S_gl + (long)t * N_ * N_;
            const unsigned short* Suh = S_uh + (long)t * N_ * N_;
            const unsigned short* Sul = S_ul + (long)t * N_ * N_;

            // ---- gate (z, r) ----
            build_xcat<<<dim3(B_ * cinp / 256, N_), dim3(256), 0, stream>>>(
                xgA0h, xgA0l, xgNh, xgNl, xt, xi16, sb, sn, cx, cin, cinp, h, nullptr);
            prop_mfma<<<dim3(Fp / 128, 4), dim3(256), 0, stream>>>(
                xgA0h, xgA0l, Sgh, Sgl, xgA1h, xgA1l,
                xgNh + sliceN, xgNl + sliceN, nullptr, nullptr, Fp);
            prop_mfma<<<dim3(Fp / 128, 4), dim3(256), 0, stream>>>(
                xgA1h, xgA1l, Sgh, Sgl, nullptr, nullptr,
                xgNh + 2 * sliceN, xgNl + 2 * sliceN, xgNh, xgNl, Fp);
            node_mfma<64><<<dim3(2 * H_ / 64, N_ / 4), dim3(256), 0, stream>>>(
                xgNh, xgNl, ne_g + (long)t * N_ * D_, Wr_g, gb, cinp, 2 * H_, 1,
                nullptr, nullptr, zr, nullptr, (long)B_ * 2 * H_, (long)2 * H_);

            // ---- candidate + h update ----
            build_xcat<<<dim3(B_ * cinp / 256, N_), dim3(256), 0, stream>>>(
                xgA0h, xgA0l, xgNh, xgNl, xt, xi16, sb, sn, cx, cin, cinp, h, zr);
            prop_mfma<<<dim3(Fp / 128, 4), dim3(256), 0, stream>>>(
                xgA0h, xgA0l, Suh, Sul, xgA1h, xgA1l,
                xgNh + sliceN, xgNl + sliceN, nullptr, nullptr, Fp);
            prop_mfma<<<dim3(Fp / 128, 4), dim3(256), 0, stream>>>(
                xgA1h, xgA1l, Suh, Sul, nullptr, nullptr,
                xgNh + 2 * sliceN, xgNl + 2 * sliceN, xgNh, xgNl, Fp);
            float* dstF; short* dstI; long dn, db;
            if (layer == 0) { dstF = nullptr; dstI = cur0 + (long)t * N_ * B_ * H_; dn = (long)B_ * H_; db = H_; }
            else            { dstF = out + (long)t * N_ * H_; dstI = nullptr; dn = H_; db = (long)T_ * N_ * H_; }
            node_mfma<32><<<dim3(H_ / 32, N_ / 4), dim3(256), 0, stream>>>(
                xgNh, xgNl, ne_u + (long)t * N_ * D_, Wr_u, ub, cinp, H_, 2,
                zr, h, dstF, dstI, dn, db);
        }
    }
}

// Round 3
// 14649.463 us; speedup vs baseline: 1.0816x; 1.0816x over previous
//
#include <hip/hip_runtime.h>

// AGGCN: split-precision bf16 MFMA (hi+lo, 3-pass) version.
// N=512, T=12, B=64, DIN=2, H=128, D=16, K=3, 2 layers.
// cin padded: layer0 130->160, layer1 256->256.
// R3: gate node_mfma = exact R0 config (OSTRIP=64, node-FAST grid: id%8=nb%8
//     keeps all ob-strips of a node on one XCD -> xgN fetched once; FETCH=107MB).
//     update node_mfma = OSTRIP=32 (R1's measured ~0.93ms win: 512 blocks,
//     2 blk/CU vs 1). No nontemporal hints (R2's hurt L2 reuse). Bit-identical math.

constexpr int N_ = 512, T_ = 12, B_ = 64, DIN_ = 2, H_ = 128, D_ = 16, K_ = 3;

typedef __attribute__((ext_vector_type(8))) short short8;
typedef __attribute__((ext_vector_type(4))) short short4v;
typedef __attribute__((ext_vector_type(4))) float floatx4;

__device__ __forceinline__ unsigned short f2bf(float f) {
    unsigned int u = __builtin_bit_cast(unsigned int, f);
    u += 0x7fffu + ((u >> 16) & 1u);
    return (unsigned short)(u >> 16);
}
__device__ __forceinline__ float bf2f(unsigned short h) {
    unsigned int u = ((unsigned int)h) << 16;
    return __builtin_bit_cast(float, u);
}
// split v ~= hi + lo (each bf16); lo captures the hi-rounding residual.
__device__ __forceinline__ void splitbf(float v, unsigned short& hh, unsigned short& ll) {
    hh = f2bf(v);
    ll = f2bf(v - bf2f(hh));
}

// ---------------------------------------------------------------------------
// LayerNorm over D=16 of (node_emb[n] + time_emb[t]) -> ne fp32
__global__ void ln_kernel(const float* __restrict__ nemb, const float* __restrict__ temb,
                          const float* __restrict__ g, const float* __restrict__ b,
                          float* __restrict__ ne) {
    int idx = blockIdx.x * 256 + threadIdx.x;
    if (idx >= T_ * N_) return;
    int t = idx / N_, n = idx % N_;
    float x[D_];
    float m = 0.f;
#pragma unroll
    for (int d = 0; d < D_; d++) { x[d] = nemb[n * D_ + d] + temb[t * D_ + d]; m += x[d]; }
    m *= (1.f / D_);
    float v = 0.f;
#pragma unroll
    for (int d = 0; d < D_; d++) { float c = x[d] - m; v += c * c; }
    v *= (1.f / D_);
    float rs = rsqrtf(v + 1e-12f);
#pragma unroll
    for (int d = 0; d < D_; d++) ne[(long)idx * D_ + d] = (x[d] - m) * rs * g[d] + b[d];
}

// ---------------------------------------------------------------------------
// S[t] = row-softmax(ne[t] @ ne[t]^T) -> bf16 hi/lo planes, row-major [dst][src]
__global__ void support_softmax(const float* __restrict__ ne,
                                unsigned short* __restrict__ Sh, unsigned short* __restrict__ Sl) {
    int rid = blockIdx.x;            // t*N + n
    int t = rid / N_, n = rid % N_;
    const float* net = ne + (long)t * N_ * D_;
    int lane = threadIdx.x;          // 64
    float r[D_];
#pragma unroll
    for (int d = 0; d < D_; d++) r[d] = net[(long)n * D_ + d];
    float v[8];
    float mx = -1e30f;
#pragma unroll
    for (int jj = 0; jj < 8; jj++) {
        const float* nj = net + (long)(jj * 64 + lane) * D_;
        float acc = 0.f;
#pragma unroll
        for (int d = 0; d < D_; d++) acc = fmaf(r[d], nj[d], acc);
        v[jj] = acc;
        mx = fmaxf(mx, acc);
    }
#pragma unroll
    for (int off = 32; off >= 1; off >>= 1) mx = fmaxf(mx, __shfl_xor(mx, off, 64));
    float s = 0.f;
#pragma unroll
    for (int jj = 0; jj < 8; jj++) { v[jj] = __expf(v[jj] - mx); s += v[jj]; }
#pragma unroll
    for (int off = 32; off >= 1; off >>= 1) s += __shfl_xor(s, off, 64);
    float inv = 1.f / s;
#pragma unroll
    for (int jj = 0; jj < 8; jj++) {
        unsigned short hh, ll;
        splitbf(v[jj] * inv, hh, ll);
        Sh[(long)rid * N_ + jj * 64 + lane] = hh;
        Sl[(long)rid * N_ + jj * 64 + lane] = ll;
    }
}

// ---------------------------------------------------------------------------
// W (D,K,cin,out) fp32 -> Wr (K,cinp,out,D) fp32, zero for i>=cin.
__global__ void reorder_W(const float* __restrict__ W, float* __restrict__ Wr,
                          int cin, int cinp, int outdim) {
    int total = K_ * cinp * outdim * D_;
    int idx = blockIdx.x * 256 + threadIdx.x;
    if (idx >= total) return;
    int d = idx & (D_ - 1);
    int rest = idx >> 4;            // (k*cinp + i)*outdim + o
    int o = rest % outdim;
    int ki = rest / outdim;
    int i = ki % cinp, kk = ki / cinp;
    float val = 0.f;
    if (i < cin) val = W[(((long)d * K_ + kk) * cin + i) * outdim + o];
    Wr[idx] = val;
}

// ---------------------------------------------------------------------------
// x0 = concat(xt, (z*)h), split bf16, dual layout:
//  xgN[n][b*cinp+c] (node-major) hi/lo;  xgA[(b*cinp+c)][n] (F-major) hi/lo.
__global__ void build_xcat(unsigned short* __restrict__ xgAh, unsigned short* __restrict__ xgAl,
                           unsigned short* __restrict__ xgNh, unsigned short* __restrict__ xgNl,
                           const void* __restrict__ xt, int xt_i16, long sb, long sn,
                           int cx, int cin, int cinp,
                           const float* __restrict__ h, const float* __restrict__ zr) {
    int n = blockIdx.y;
    int idx = blockIdx.x * 256 + threadIdx.x;   // b*cinp + c (grid exact)
    int b = idx / cinp, c = idx - b * cinp;
    float v = 0.f;
    if (c < cx) {
        v = xt_i16 ? (float)((const short*)xt)[(long)b * sb + (long)n * sn + c] * (1.f / 32767.f)
                   : ((const float*)xt)[(long)b * sb + (long)n * sn + c];
    } else if (c < cin) {
        int q = c - cx;
        v = h[((long)n * B_ + b) * H_ + q];
        if (zr) v *= zr[((long)n * B_ + b) * (2 * H_) + q];
    }
    unsigned short hh, ll;
    splitbf(v, hh, ll);
    xgNh[(long)n * B_ * cinp + idx] = hh;
    xgNl[(long)n * B_ * cinp + idx] = ll;
    xgAh[(long)idx * N_ + n] = hh;
    xgAl[(long)idx * N_ + n] = ll;
}

// ---------------------------------------------------------------------------
// Graph prop, split bf16 3-pass MFMA: out[f,dst] = sum_src X[f,src]*S[dst,src]
// 128x128 tile, BK=32, 4 waves of 64x64 each.
// outN hi/lo: [dst][f]. outA hi/lo: [f][dst] (P1 only).
// subN hi/lo: Chebyshev  val = 2*acc - x0  (P2 only).
__global__ __launch_bounds__(256) void prop_mfma(
    const unsigned short* __restrict__ XAh, const unsigned short* __restrict__ XAl,
    const unsigned short* __restrict__ Sh,  const unsigned short* __restrict__ Sl,
    unsigned short* __restrict__ outAh, unsigned short* __restrict__ outAl,
    unsigned short* __restrict__ outNh, unsigned short* __restrict__ outNl,
    const unsigned short* __restrict__ subNh, const unsigned short* __restrict__ subNl,
    int Fp) {
    __shared__ short Ash[128 * 40];
    __shared__ short Asl[128 * 40];
    __shared__ short Ssh[128 * 40];
    __shared__ short Ssl[128 * 40];
    int tid = threadIdx.x;
    int bm = blockIdx.x * 128, bn = blockIdx.y * 128;
    int w = tid >> 6, lane15 = tid & 15, quad = (tid >> 4) & 3;
    int mw = (w & 1) * 64, nw = (w >> 1) * 64;
    floatx4 acc[4][4];
#pragma unroll
    for (int mt = 0; mt < 4; mt++)
#pragma unroll
        for (int nt = 0; nt < 4; nt++) acc[mt][nt] = (floatx4){0.f, 0.f, 0.f, 0.f};

    for (int s0 = 0; s0 < N_; s0 += 32) {
#pragma unroll
        for (int p = 0; p < 2; p++) {
            int c = tid + p * 256;
            int row = c >> 2, col = (c & 3) * 8;
            *(short8*)&Ash[row * 40 + col] = *(const short8*)(XAh + (long)(bm + row) * N_ + s0 + col);
            *(short8*)&Asl[row * 40 + col] = *(const short8*)(XAl + (long)(bm + row) * N_ + s0 + col);
            *(short8*)&Ssh[row * 40 + col] = *(const short8*)(Sh + (long)(bn + row) * N_ + s0 + col);
            *(short8*)&Ssl[row * 40 + col] = *(const short8*)(Sl + (long)(bn + row) * N_ + s0 + col);
        }
        __syncthreads();
        short8 ah[4], al[4];
#pragma unroll
        for (int mt = 0; mt < 4; mt++) {
            ah[mt] = *(const short8*)&Ash[(mw + mt * 16 + lane15) * 40 + quad * 8];
            al[mt] = *(const short8*)&Asl[(mw + mt * 16 + lane15) * 40 + quad * 8];
        }
#pragma unroll
        for (int nt = 0; nt < 4; nt++) {
            short8 bh = *(const short8*)&Ssh[(nw + nt * 16 + lane15) * 40 + quad * 8];
            short8 bl = *(const short8*)&Ssl[(nw + nt * 16 + lane15) * 40 + quad * 8];
#pragma unroll
            for (int mt = 0; mt < 4; mt++) {
                acc[mt][nt] = __builtin_amdgcn_mfma_f32_16x16x32_bf16(ah[mt], bh, acc[mt][nt], 0, 0, 0);
                acc[mt][nt] = __builtin_amdgcn_mfma_f32_16x16x32_bf16(al[mt], bh, acc[mt][nt], 0, 0, 0);
                acc[mt][nt] = __builtin_amdgcn_mfma_f32_16x16x32_bf16(ah[mt], bl, acc[mt][nt], 0, 0, 0);
            }
        }
        __syncthreads();
    }

#pragma unroll
    for (int mt = 0; mt < 4; mt++) {
        int f0 = bm + mw + mt * 16 + quad * 4;
#pragma unroll
        for (int nt = 0; nt < 4; nt++) {
            int dst = bn + nw + nt * 16 + lane15;
            float v[4] = {acc[mt][nt][0], acc[mt][nt][1], acc[mt][nt][2], acc[mt][nt][3]};
            if (subNh) {
                ushort4 sh4 = *(const ushort4*)(subNh + (long)dst * Fp + f0);
                ushort4 sl4 = *(const ushort4*)(subNl + (long)dst * Fp + f0);
                v[0] = 2.f * v[0] - (bf2f(sh4.x) + bf2f(sl4.x));
                v[1] = 2.f * v[1] - (bf2f(sh4.y) + bf2f(sl4.y));
                v[2] = 2.f * v[2] - (bf2f(sh4.z) + bf2f(sl4.z));
                v[3] = 2.f * v[3] - (bf2f(sh4.w) + bf2f(sl4.w));
            }
            ushort4 oh, ol;
            splitbf(v[0], oh.x, ol.x); splitbf(v[1], oh.y, ol.y);
            splitbf(v[2], oh.z, ol.z); splitbf(v[3], oh.w, ol.w);
            *(ushort4*)(outNh + (long)dst * Fp + f0) = oh;
            *(ushort4*)(outNl + (long)dst * Fp + f0) = ol;
            if (outAh) {
                unsigned short* pah = outAh + (long)f0 * N_ + dst;
                unsigned short* pal = outAl + (long)f0 * N_ + dst;
                pah[0] = oh.x; pah[N_] = oh.y; pah[2 * N_] = oh.z; pah[3 * N_] = oh.w;
                pal[0] = ol.x; pal[N_] = ol.y; pal[2 * N_] = ol.z; pal[3 * N_] = ol.w;
            }
        }
    }
}

// ---------------------------------------------------------------------------
// Fused node GEMM, split precision. Block = 4 nodes (1/wave) x OSTRIP o-cols.
// Pool Wp[i][o] = sum_d ne[n,d]*Wr[k,i,o,d] in fp32 (once per element),
// split into LDS hi/lo; 3-pass 16x16x32 bf16 MFMA vs xgN hi/lo.
// Grid = (nb FAST, ob): id%8 = nb%8 -> all ob-strips of a node share one XCD,
// so xgN is fetched once per node (TCC-side); co-resident same-ob blocks
// stream Wr in near-lockstep so the Wr front stays L2-resident.
// mode 1: sigmoid -> zrOut(dstF). mode 2: tanh, h'=r*h+(1-r)*hc -> h + dstF|dstI.
template <int OSTRIP>
__global__ __launch_bounds__(256) void node_mfma(
    const unsigned short* __restrict__ xgNh, const unsigned short* __restrict__ xgNl,
    const float* __restrict__ ne_t,
    const float* __restrict__ Wr, const float* __restrict__ bpool,
    int cinp, int outdim, int mode,
    const float* __restrict__ zrIn, float* __restrict__ h,
    float* __restrict__ dstF, short* __restrict__ dstI,
    long dn, long db) {
    constexpr int NT = OSTRIP / 16;     // n-tiles per wave (4 or 2)
    constexpr int IG = 256 / OSTRIP;    // i-groups covering the 32-slab (4 or 8)
    constexpr int IL = 32 / IG;         // i's per thread (8 or 4)
    __shared__ short Wph[4 * OSTRIP * 40];
    __shared__ short Wpl[4 * OSTRIP * 40];
    int tid = threadIdx.x;
    int n0 = blockIdx.x * 4;            // FAST grid dim (node-major)
    int ob = blockIdx.y * OSTRIP;
    int w = tid >> 6, lane15 = tid & 15, quad = (tid >> 4) & 3;
    int oo = tid & (OSTRIP - 1);        // o within strip
    int iq = tid / OSTRIP;              // i-group
    int Fp = B_ * cinp;
    int myn = n0 + w;

    float ner[4][16];
#pragma unroll
    for (int g = 0; g < 4; g++)
#pragma unroll
        for (int d = 0; d < D_; d++) ner[g][d] = ne_t[(long)(n0 + g) * D_ + d];

    float bias[NT];
#pragma unroll
    for (int nt = 0; nt < NT; nt++) {
        int o = ob + nt * 16 + lane15;
        float bv = 0.f;
#pragma unroll
        for (int d = 0; d < D_; d++) bv = fmaf(ner[w][d], bpool[(long)d * outdim + o], bv);
        bias[nt] = bv;
    }
    floatx4 acc[4][NT];
#pragma unroll
    for (int mt = 0; mt < 4; mt++)
#pragma unroll
        for (int nt = 0; nt < NT; nt++) acc[mt][nt] = (floatx4){bias[nt], bias[nt], bias[nt], bias[nt]};

    for (int kk = 0; kk < K_; kk++) {
        const unsigned short* xbh = xgNh + ((long)kk * N_ + myn) * Fp;
        const unsigned short* xbl = xgNl + ((long)kk * N_ + myn) * Fp;
        for (int i0 = 0; i0 < cinp; i0 += 32) {
            // ---- fp32 pooling: thread covers o=ob+oo, i = i0 + iq*IL + il, all 4 nodes ----
            float pool[4][IL];
#pragma unroll
            for (int g = 0; g < 4; g++)
#pragma unroll
                for (int il = 0; il < IL; il++) pool[g][il] = 0.f;
#pragma unroll
            for (int il = 0; il < IL; il++) {
                const float* wp = Wr + ((long)(kk * cinp + i0 + iq * IL + il) * outdim + ob + oo) * D_;
                float4 w0 = *(const float4*)(wp + 0);
                float4 w1 = *(const float4*)(wp + 4);
                float4 w2 = *(const float4*)(wp + 8);
                float4 w3 = *(const float4*)(wp + 12);
                float wv[16] = {w0.x, w0.y, w0.z, w0.w, w1.x, w1.y, w1.z, w1.w,
                                w2.x, w2.y, w2.z, w2.w, w3.x, w3.y, w3.z, w3.w};
#pragma unroll
                for (int d = 0; d < D_; d++)
#pragma unroll
                    for (int g = 0; g < 4; g++) pool[g][il] = fmaf(ner[g][d], wv[d], pool[g][il]);
            }
            __syncthreads();   // previous slab's frag reads complete
#pragma unroll
            for (int g = 0; g < 4; g++) {
                if constexpr (IL == 8) {
                    short8 vh, vl;
#pragma unroll
                    for (int il = 0; il < 8; il++) {
                        unsigned short hh, ll;
                        splitbf(pool[g][il], hh, ll);
                        vh[il] = (short)hh; vl[il] = (short)ll;
                    }
                    *(short8*)&Wph[(g * OSTRIP + oo) * 40 + iq * 8] = vh;
                    *(short8*)&Wpl[(g * OSTRIP + oo) * 40 + iq * 8] = vl;
                } else {
                    short4v vh, vl;
#pragma unroll
                    for (int il = 0; il < 4; il++) {
                        unsigned short hh, ll;
                        splitbf(pool[g][il], hh, ll);
                        vh[il] = (short)hh; vl[il] = (short)ll;
                    }
                    *(short4v*)&Wph[(g * OSTRIP + oo) * 40 + iq * 4] = vh;
                    *(short4v*)&Wpl[(g * OSTRIP + oo) * 40 + iq * 4] = vl;
                }
            }
            __syncthreads();
            // ---- 3-pass MFMA ----
            short8 ah[4], al[4];
#pragma unroll
            for (int mt = 0; mt < 4; mt++) {
                ah[mt] = *(const short8*)(xbh + (long)(mt * 16 + lane15) * cinp + i0 + quad * 8);
                al[mt] = *(const short8*)(xbl + (long)(mt * 16 + lane15) * cinp + i0 + quad * 8);
            }
#pragma unroll
            for (int nt = 0; nt < NT; nt++) {
                short8 bh = *(const short8*)&Wph[(w * OSTRIP + nt * 16 + lane15) * 40 + quad * 8];
                short8 bl = *(const short8*)&Wpl[(w * OSTRIP + nt * 16 + lane15) * 40 + quad * 8];
#pragma unroll
                for (int mt = 0; mt < 4; mt++) {
                    acc[mt][nt] = __builtin_amdgcn_mfma_f32_16x16x32_bf16(ah[mt], bh, acc[mt][nt], 0, 0, 0);
                    acc[mt][nt] = __builtin_amdgcn_mfma_f32_16x16x32_bf16(al[mt], bh, acc[mt][nt], 0, 0, 0);
                    acc[mt][nt] = __builtin_amdgcn_mfma_f32_16x16x32_bf16(ah[mt], bl, acc[mt][nt], 0, 0, 0);
                }
            }
        }
    }

#pragma unroll
    for (int mt = 0; mt < 4; mt++) {
        int b0 = mt * 16 + quad * 4;
#pragma unroll
        for (int nt = 0; nt < NT; nt++) {
            int o = ob + nt * 16 + lane15;
#pragma unroll
            for (int r = 0; r < 4; r++) {
                float v = acc[mt][nt][r];
                int bb = b0 + r;
                if (mode == 1) {
                    float s = 1.f / (1.f + __expf(-v));
                    dstF[(long)myn * dn + (long)bb * db + o] = s;
                } else {
                    float hc = tanhf(v);
                    long bi = (long)myn * B_ + bb;
                    float rr = zrIn[bi * (2 * H_) + H_ + o];
                    float hn = rr * h[bi * H_ + o] + (1.f - rr) * hc;
                    h[bi * H_ + o] = hn;
                    if (dstF) dstF[(long)myn * dn + (long)bb * db + o] = hn;
                    else {
                        int q = __float2int_rn(hn * 32767.f);
                        q = q > 32767 ? 32767 : (q < -32767 ? -32767 : q);
                        dstI[(long)myn * dn + (long)bb * db + o] = (short)q;
                    }
                }
            }
        }
    }
}

// ---------------------------------------------------------------------------
extern "C" void kernel_launch(void* const* d_in, const int* in_sizes, int n_in,
                              void* d_out, int out_size, void* d_ws, size_t ws_size,
                              hipStream_t stream) {
    const float* source   = (const float*)d_in[0];
    const float* node_emb = (const float*)d_in[1];
    const float* time_emb = (const float*)d_in[2];
    float* out = (float*)d_out;

    char* p = (char*)d_ws;
    auto carve = [&](size_t bytes) { char* r = p; p += (bytes + 255) & ~255ull; return r; };
    float*          ne_g  = (float*)carve((size_t)T_ * N_ * D_ * 4);
    float*          ne_u  = (float*)carve((size_t)T_ * N_ * D_ * 4);
    unsigned short* S_gh  = (unsigned short*)carve((size_t)T_ * N_ * N_ * 2);
    unsigned short* S_gl  = (unsigned short*)carve((size_t)T_ * N_ * N_ * 2);
    unsigned short* S_uh  = (unsigned short*)carve((size_t)T_ * N_ * N_ * 2);
    unsigned short* S_ul  = (unsigned short*)carve((size_t)T_ * N_ * N_ * 2);
    float*          Wr_g  = (float*)carve((size_t)K_ * 256 * 256 * D_ * 4);
    float*          Wr_u  = (float*)carve((size_t)K_ * 256 * 128 * D_ * 4);
    unsigned short* xgA0h = (unsigned short*)carve((size_t)64 * 256 * N_ * 2);
    unsigned short* xgA0l = (unsigned short*)carve((size_t)64 * 256 * N_ * 2);
    unsigned short* xgA1h = (unsigned short*)carve((size_t)64 * 256 * N_ * 2);
    unsigned short* xgA1l = (unsigned short*)carve((size_t)64 * 256 * N_ * 2);
    unsigned short* xgNh  = (unsigned short*)carve((size_t)K_ * N_ * 64 * 256 * 2);
    unsigned short* xgNl  = (unsigned short*)carve((size_t)K_ * N_ * 64 * 256 * 2);
    float*          zr    = (float*)carve((size_t)N_ * B_ * 2 * H_ * 4);
    float*          h     = (float*)carve((size_t)N_ * B_ * H_ * 4);
    short*          cur0  = (short*)carve((size_t)T_ * N_ * B_ * H_ * 2);
    if ((size_t)(p - (char*)d_ws) > ws_size) return;  // ws guard (~364 MB)

    for (int layer = 0; layer < 2; ++layer) {
        const float* gW   = (const float*)d_in[3 + layer * 8 + 0];
        const float* gb   = (const float*)d_in[3 + layer * 8 + 1];
        const float* glng = (const float*)d_in[3 + layer * 8 + 2];
        const float* glnb = (const float*)d_in[3 + layer * 8 + 3];
        const float* uW   = (const float*)d_in[3 + layer * 8 + 4];
        const float* ub   = (const float*)d_in[3 + layer * 8 + 5];
        const float* ulng = (const float*)d_in[3 + layer * 8 + 6];
        const float* ulnb = (const float*)d_in[3 + layer * 8 + 7];
        const int cin  = (layer == 0) ? (DIN_ + H_) : (2 * H_);
        const int cinp = (layer == 0) ? 160 : 256;
        const int cx   = (layer == 0) ? DIN_ : H_;
        const int Fp   = B_ * cinp;
        const long sliceN = (long)N_ * Fp;

        ln_kernel<<<dim3(24), dim3(256), 0, stream>>>(node_emb, time_emb, glng, glnb, ne_g);
        ln_kernel<<<dim3(24), dim3(256), 0, stream>>>(node_emb, time_emb, ulng, ulnb, ne_u);
        support_softmax<<<dim3(T_ * N_), dim3(64), 0, stream>>>(ne_g, S_gh, S_gl);
        support_softmax<<<dim3(T_ * N_), dim3(64), 0, stream>>>(ne_u, S_uh, S_ul);
        reorder_W<<<dim3(K_ * cinp * (2 * H_) * D_ / 256), dim3(256), 0, stream>>>(gW, Wr_g, cin, cinp, 2 * H_);
        reorder_W<<<dim3(K_ * cinp * H_ * D_ / 256), dim3(256), 0, stream>>>(uW, Wr_u, cin, cinp, H_);
        hipMemsetAsync(h, 0, (size_t)N_ * B_ * H_ * sizeof(float), stream);

        for (int t = 0; t < T_; ++t) {
            const void* xt; long sb, sn; int xi16;
            if (layer == 0) { xt = source + (long)t * N_ * DIN_; sb = (long)T_ * N_ * DIN_; sn = DIN_; xi16 = 0; }
            else            { xt = cur0 + (long)t * N_ * B_ * H_; sb = H_; sn = (long)B_ * H_; xi16 = 1; }
            const unsigned short* Sgh = S_gh + (long)t * N_ * N_;
            const unsigned short* Sgl = S_gl + (long)t * N_ * N_;
            const unsigned short* Suh = S_uh + (long)t * N_ * N_;
            const unsigned short* Sul = S_ul + (long)t * N_ * N_;

            // ---- gate (z, r) ----
            build_xcat<<<dim3(B_ * cinp / 256, N_), dim3(256), 0, stream>>>(
                xgA0h, xgA0l, xgNh, xgNl, xt, xi16, sb, sn, cx, cin, cinp, h, nullptr);
            prop_mfma<<<dim3(Fp / 128, 4), dim3(256), 0, stream>>>(
                xgA0h, xgA0l, Sgh, Sgl, xgA1h, xgA1l,
                xgNh + sliceN, xgNl + sliceN, nullptr, nullptr, Fp);
            prop_mfma<<<dim3(Fp / 128, 4), dim3(256), 0, stream>>>(
                xgA1h, xgA1l, Sgh, Sgl, nullptr, nullptr,
                xgNh + 2 * sliceN, xgNl + 2 * sliceN, xgNh, xgNl, Fp);
            node_mfma<64><<<dim3(N_ / 4, 2 * H_ / 64), dim3(256), 0, stream>>>(
                xgNh, xgNl, ne_g + (long)t * N_ * D_, Wr_g, gb, cinp, 2 * H_, 1,
                nullptr, nullptr, zr, nullptr, (long)B_ * 2 * H_, (long)2 * H_);

            // ---- candidate + h update ----
            build_xcat<<<dim3(B_ * cinp / 256, N_), dim3(256), 0, stream>>>(
                xgA0h, xgA0l, xgNh, xgNl, xt, xi16, sb, sn, cx, cin, cinp, h, zr);
            prop_mfma<<<dim3(Fp / 128, 4), dim3(256), 0, stream>>>(
                xgA0h, xgA0l, Suh, Sul, xgA1h, xgA1l,
                xgNh + sliceN, xgNl + sliceN, nullptr, nullptr, Fp);
            prop_mfma<<<dim3(Fp / 128, 4), dim3(256), 0, stream>>>(
                xgA1h, xgA1l, Suh, Sul, nullptr, nullptr,
                xgNh + 2 * sliceN, xgNl + 2 * sliceN, xgNh, xgNl, Fp);
            float* dstF; short* dstI; long dn, db;
            if (layer == 0) { dstF = nullptr; dstI = cur0 + (long)t * N_ * B_ * H_; dn = (long)B_ * H_; db = H_; }
            else            { dstF = out + (long)t * N_ * H_; dstI = nullptr; dn = H_; db = (long)T_ * N_ * H_; }
            node_mfma<32><<<dim3(N_ / 4, H_ / 32), dim3(256), 0, stream>>>(
                xgNh, xgNl, ne_u + (long)t * N_ * D_, Wr_u, ub, cinp, H_, 2,
                zr, h, dstF, dstI, dn, db);
        }
    }
}